// Round 13
// baseline (480.406 us; speedup 1.0000x reference)
//
#include <hip/hip_runtime.h>
#include <hip/hip_bf16.h>
#include <hip/hip_cooperative_groups.h>

namespace cg = cooperative_groups;

typedef __bf16 bf16;
typedef bf16 bf16x4 __attribute__((ext_vector_type(4)));
typedef bf16 bf16x8 __attribute__((ext_vector_type(8)));
typedef float floatx4 __attribute__((ext_vector_type(4)));

#define GLOBAL_AS __attribute__((address_space(1)))
#define LDS_AS __attribute__((address_space(3)))

// ---------------------------------------------------------------------------
// Phase 0: f32 -> bf16 conversion (grid-stride, float4 granular).
// ---------------------------------------------------------------------------
__device__ __forceinline__
void cvt_phase(const float* __restrict__ s0, const float* __restrict__ s1,
               const float* __restrict__ s2, bf16* __restrict__ d0,
               bf16* __restrict__ d1, bf16* __restrict__ d2,
               int n0, int n1, int n2)
{
    const int total = n0 + n1 + n2;
    for (int t = blockIdx.x * 256 + threadIdx.x; t < total;
         t += gridDim.x * 256) {
        const float* s; bf16* d; int i;
        if (t < n0)           { s = s0; d = d0; i = t; }
        else if (t < n0 + n1) { s = s1; d = d1; i = t - n0; }
        else                  { s = s2; d = d2; i = t - n0 - n1; }
        float4 v = ((const float4*)s)[i];
        bf16x4 o = { (bf16)v.x, (bf16)v.y, (bf16)v.z, (bf16)v.w };
        ((bf16x4*)d)[i] = o;
    }
}

// ---------------------------------------------------------------------------
// One GEMM tile: C[m][n] = sum_k A[m][k]*W[n][k] (+bias). bf16 operands,
// async global_load_lds(16B) staging, 4x4 / 2x4 16x16x32 MFMA (R8-R11 proven).
// ---------------------------------------------------------------------------
template<typename CT, int TM, int K, int LDA, int LDC>
__device__ __forceinline__
void gemm_tile(const bf16* __restrict__ A, const bf16* __restrict__ W,
               CT* __restrict__ C, const float* __restrict__ bias,
               bf16* As, bf16* Bs, int row0, int col0)
{
    constexpr int MI = TM / 32;
    const int tid  = threadIdx.x;
    const int lane = tid & 63;
    const int wave = tid >> 6;
    const int wm = (wave & 1) * (TM / 2);
    const int wn = (wave >> 1) * 64;

    floatx4 acc[MI][4] = {};
    const int fr = lane & 15;
    const int fk = (lane >> 4) * 8;
    const int lr = lane >> 2;        // staging: row within 16-row chunk
    const int lk = (lane & 3) * 8;   //          k offset within row

    for (int k0 = 0; k0 < K; k0 += 32) {
        constexpr int CAW = TM / 64;     // A chunks per wave
        #pragma unroll
        for (int c = 0; c < CAW; ++c) {
            const int chunk = wave * CAW + c;
            const int r = chunk * 16 + lr;
            const bf16* gA = A + (size_t)(row0 + r) * LDA + k0 + lk;
            __builtin_amdgcn_global_load_lds((const GLOBAL_AS void*)gA,
                                             (LDS_AS void*)(As + chunk * 512),
                                             16, 0, 0);
        }
        #pragma unroll
        for (int c = 0; c < 2; ++c) {
            const int chunk = wave * 2 + c;
            const int r = chunk * 16 + lr;
            const bf16* gB = W + (size_t)(col0 + r) * K + k0 + lk;
            __builtin_amdgcn_global_load_lds((const GLOBAL_AS void*)gB,
                                             (LDS_AS void*)(Bs + chunk * 512),
                                             16, 0, 0);
        }
        __syncthreads();

        bf16x8 af[MI], bfr[4];
        #pragma unroll
        for (int i = 0; i < MI; ++i)
            af[i]  = *(const bf16x8*)(As + (wm + i * 16 + fr) * 32 + fk);
        #pragma unroll
        for (int j = 0; j < 4; ++j)
            bfr[j] = *(const bf16x8*)(Bs + (wn + j * 16 + fr) * 32 + fk);
        #pragma unroll
        for (int i = 0; i < MI; ++i)
            #pragma unroll
            for (int j = 0; j < 4; ++j)
                acc[i][j] = __builtin_amdgcn_mfma_f32_16x16x32_bf16(
                    af[i], bfr[j], acc[i][j], 0, 0, 0);

        __syncthreads();
    }

    const int fc  = lane & 15;
    const int fr4 = (lane >> 4) * 4;
    #pragma unroll
    for (int i = 0; i < MI; ++i) {
        #pragma unroll
        for (int j = 0; j < 4; ++j) {
            const int col = col0 + wn + j * 16 + fc;
            const float b = bias ? bias[col] : 0.0f;
            #pragma unroll
            for (int r = 0; r < 4; ++r) {
                const int row = row0 + wm + i * 16 + fr4 + r;
                C[(size_t)row * LDC + col] = (CT)(acc[i][j][r] + b);
            }
        }
    }
}

// ---------------------------------------------------------------------------
// One attention block (4 waves, one (b,h,16-i-tile) per wave).
// LDS now wave-private only: Vt 4x64x40 @0 (20480 B), Ps 4x16x40 @20480
// (5120 B) -> 25600 B. K/Q fragments read direct from global (k-contiguous).
// No __syncthreads needed: each wave touches only its own LDS slice, and
// same-wave DS ops are in-order. Math identical to R7-R11 verified kernel.
// ---------------------------------------------------------------------------
__device__ __forceinline__
void attn_block(const bf16* __restrict__ qkv, bf16* __restrict__ aout,
                char* smem, int blk)
{
    const int w    = threadIdx.x >> 6;
    const int lane = threadIdx.x & 63;
    const int c    = lane & 15;
    const int q    = lane >> 4;
    const int wid  = blk * 4 + w;          // 0..3071
    const int it   = wid & 127;
    const int bh   = wid >> 7;             // 0..23
    const int h    = bh % 12;
    const int b    = bh / 12;
    const int I0   = it * 16;
    const int bbase = b * 2048;
    const int j0   = I0 - 7;

    bf16* Vt = (bf16*)smem           + w * (64 * 40);
    bf16* Ps = (bf16*)(smem + 20480) + w * (16 * 40);

    // stage V^T (wave-private slice)
    #pragma unroll
    for (int itr = 0; itr < 4; ++itr) {
        int idx = itr * 64 + lane;        // 0..255
        int row = idx >> 3;               // 0..31
        int dc  = (idx & 7) * 8;          // 0,8,...,56
        int jc  = j0 + row; jc = jc < 0 ? 0 : (jc > 2047 ? 2047 : jc);
        bf16x8 vv = *(const bf16x8*)(qkv + (size_t)(bbase + jc) * 2304
                                     + 1536 + h * 64 + dc);
        #pragma unroll
        for (int e = 0; e < 8; ++e) Vt[(dc + e) * 40 + row] = vv[e];
    }

    // Q fragments (A-layout) from global
    const bf16* qrow = qkv + (size_t)(bbase + I0 + c) * 2304 + h * 64;
    bf16x8 aq0 = *(const bf16x8*)(qrow + q * 8);
    bf16x8 aq1 = *(const bf16x8*)(qrow + 32 + q * 8);

    // S = Q K^T; K B-fragments direct from global (row j0+t*16+c, clamped)
    floatx4 st[2] = {};
    #pragma unroll
    for (int t = 0; t < 2; ++t) {
        int jc = j0 + t * 16 + c; jc = jc < 0 ? 0 : (jc > 2047 ? 2047 : jc);
        const bf16* krow = qkv + (size_t)(bbase + jc) * 2304 + 768 + h * 64;
        bf16x8 k0 = *(const bf16x8*)(krow + q * 8);
        bf16x8 k1 = *(const bf16x8*)(krow + 32 + q * 8);
        st[t] = __builtin_amdgcn_mfma_f32_16x16x32_bf16(aq0, k0, st[t], 0, 0, 0);
        st[t] = __builtin_amdgcn_mfma_f32_16x16x32_bf16(aq1, k1, st[t], 0, 0, 0);
    }

    float s[2][4];
    #pragma unroll
    for (int t = 0; t < 2; ++t)
        #pragma unroll
        for (int r = 0; r < 4; ++r) {
            int il = q * 4 + r;
            int jl = t * 16 + c;
            int ja = j0 + jl;
            bool valid = (jl >= il) && (jl <= il + 14) && (ja >= 0) && (ja < 2048);
            s[t][r] = valid ? st[t][r] * 0.125f : -1e30f;
        }

    float l[4], p[2][4];
    #pragma unroll
    for (int r = 0; r < 4; ++r) {
        float m2 = fmaxf(s[0][r], s[1][r]);
        #pragma unroll
        for (int mk = 1; mk < 16; mk <<= 1) m2 = fmaxf(m2, __shfl_xor(m2, mk, 64));
        p[0][r] = __expf(s[0][r] - m2);
        p[1][r] = __expf(s[1][r] - m2);
        float l2 = p[0][r] + p[1][r];
        #pragma unroll
        for (int mk = 1; mk < 16; mk <<= 1) l2 += __shfl_xor(l2, mk, 64);
        l[r] = l2;
    }

    // P: C-layout -> A-layout via wave-private LDS (in-order same-wave DS)
    #pragma unroll
    for (int r = 0; r < 4; ++r) {
        Ps[(q * 4 + r) * 40 + c]      = (bf16)p[0][r];
        Ps[(q * 4 + r) * 40 + 16 + c] = (bf16)p[1][r];
    }

    bf16x8 ap = *(const bf16x8*)(&Ps[c * 40 + q * 8]);
    floatx4 ov[4];
    #pragma unroll
    for (int nt = 0; nt < 4; ++nt) {
        bf16x8 vf = *(const bf16x8*)(&Vt[(nt * 16 + c) * 40 + q * 8]);
        floatx4 z = {};
        ov[nt] = __builtin_amdgcn_mfma_f32_16x16x32_bf16(ap, vf, z, 0, 0, 0);
    }

    float rl[4];
    #pragma unroll
    for (int r = 0; r < 4; ++r) rl[r] = 1.0f / l[r];
    #pragma unroll
    for (int r = 0; r < 4; ++r) {
        bf16* orow = aout + (size_t)(bbase + I0 + q * 4 + r) * 768 + h * 64;
        #pragma unroll
        for (int nt = 0; nt < 4; ++nt)
            orow[nt * 16 + c] = (bf16)(ov[nt][r] * rl[r]);
    }
}

// ---------------------------------------------------------------------------
// Fused cooperative kernel: cvt -> GEMM1 -> attn -> GEMM2, grid.sync between.
// 512 blocks; LDS 25600 B -> 2 blocks/CU even under 64 KB/CU accounting.
// ---------------------------------------------------------------------------
struct FArgs {
    const float* x; const float* wq; const float* wp; const float* bp;
    float* out; bf16* qkv; bf16* aout; bf16* xb; bf16* wqb; bf16* wpb;
};

__global__ __launch_bounds__(256, 2)
void fused(FArgs a)
{
    __shared__ __align__(16) char smem[25600];
    bf16* As = (bf16*)smem;
    bf16* Bs = (bf16*)(smem + 8192);
    cg::grid_group grid = cg::this_grid();

    // P0: convert x, w_qkv, w_proj to bf16
    cvt_phase(a.x, a.wq, a.wp, a.xb, a.wqb, a.wpb, 786432, 442368, 147456);
    __threadfence();
    grid.sync();

    // P1: qkv = xb @ wqb^T   (576 tiles, TM=128)
    for (int t = blockIdx.x; t < 576; t += gridDim.x)
        gemm_tile<bf16, 128, 768, 768, 2304>(a.xb, a.wqb, a.qkv, nullptr,
                                             As, Bs, (t & 31) * 128, (t >> 5) * 128);
    __threadfence();
    grid.sync();

    // P2: local-window attention (768 logical blocks)
    for (int t = blockIdx.x; t < 768; t += gridDim.x)
        attn_block(a.qkv, a.aout, smem, t);
    __threadfence();
    grid.sync();

    // P3: out = aout @ wpb^T + b_proj   (384 tiles, TM=64)
    for (int t = blockIdx.x; t < 384; t += gridDim.x)
        gemm_tile<float, 64, 768, 768, 768>(a.aout, a.wpb, a.out, a.bp,
                                            As, Bs, (t & 63) * 64, (t >> 6) * 128);
}

// ---------------------------------------------------------------------------
// Fallback standalone kernels (R11-equivalent path, same device bodies).
// ---------------------------------------------------------------------------
__global__ __launch_bounds__(256)
void cvt3_k(const float* s0, const float* s1, const float* s2,
            bf16* d0, bf16* d1, bf16* d2)
{ cvt_phase(s0, s1, s2, d0, d1, d2, 786432, 442368, 147456); }

__global__ __launch_bounds__(256, 2)
void gemm1_k(const bf16* A, const bf16* W, bf16* C)
{
    __shared__ __align__(16) bf16 As[128 * 32];
    __shared__ __align__(16) bf16 Bs[128 * 32];
    gemm_tile<bf16, 128, 768, 768, 2304>(A, W, C, nullptr, As, Bs,
                                         blockIdx.x * 128, blockIdx.y * 128);
}

__global__ __launch_bounds__(256)
void attn_k(const bf16* qkv, bf16* aout)
{
    __shared__ __align__(16) char smem[25600];
    attn_block(qkv, aout, smem, blockIdx.x);
}

__global__ __launch_bounds__(256, 2)
void gemm2_k(const bf16* A, const bf16* W, float* C, const float* bias)
{
    __shared__ __align__(16) bf16 As[64 * 32];
    __shared__ __align__(16) bf16 Bs[128 * 32];
    gemm_tile<float, 64, 768, 768, 768>(A, W, C, bias, As, Bs,
                                        blockIdx.x * 64, blockIdx.y * 128);
}

// ---------------------------------------------------------------------------
extern "C" void kernel_launch(void* const* d_in, const int* in_sizes, int n_in,
                              void* d_out, int out_size, void* d_ws, size_t ws_size,
                              hipStream_t stream)
{
    const float* x      = (const float*)d_in[0];  // [4096][768] f32
    const float* w_qkv  = (const float*)d_in[1];  // [2304][768] f32
    const float* w_proj = (const float*)d_in[2];  // [768][768]  f32
    const float* b_proj = (const float*)d_in[3];  // [768]       f32
    float* out = (float*)d_out;                   // [4096][768] f32

    bf16* qkv  = (bf16*)d_ws;                     // [4096][2304]
    bf16* aout = qkv  + (size_t)4096 * 2304;      // [4096][768]
    bf16* xb   = aout + (size_t)4096 * 768;       // [4096][768]
    bf16* wqb  = xb   + (size_t)4096 * 768;       // [2304][768]
    bf16* wpb  = wqb  + (size_t)2304 * 768;       // [768][768]

    bool done = false;
    FArgs a{ x, w_qkv, w_proj, b_proj, out, qkv, aout, xb, wqb, wpb };
    void* params[] = { (void*)&a };
    if (hipLaunchCooperativeKernel((void*)fused, dim3(512), dim3(256),
                                   params, 0, stream) == hipSuccess)
        done = true;

    if (!done) {
        // R11-equivalent 4-dispatch path (122.9 us proven)
        cvt3_k<<<dim3(5376), 256, 0, stream>>>(x, w_qkv, w_proj, xb, wqb, wpb);
        gemm1_k<<<dim3(32, 18), 256, 0, stream>>>(xb, wqb, qkv);
        attn_k<<<dim3(768), 256, 0, stream>>>(qkv, aout);
        gemm2_k<<<dim3(64, 6), 256, 0, stream>>>(aout, wpb, out, b_proj);
    }
}

// Round 14
// 125.018 us; speedup vs baseline: 3.8427x; 3.8427x over previous
//
#include <hip/hip_runtime.h>
#include <hip/hip_bf16.h>

typedef __bf16 bf16;
typedef bf16 bf16x4 __attribute__((ext_vector_type(4)));
typedef bf16 bf16x8 __attribute__((ext_vector_type(8)));
typedef float floatx4 __attribute__((ext_vector_type(4)));

#define GLOBAL_AS __attribute__((address_space(1)))
#define LDS_AS __attribute__((address_space(3)))

// ---------------------------------------------------------------------------
// f32 -> bf16 conversion (grid-stride, float4 granular). R9/R10 A/B-proven
// cheaper than cvt-in-GEMM-staging (x re-read 18x, weights 32-64x).
// ---------------------------------------------------------------------------
__device__ __forceinline__
void cvt_phase(const float* __restrict__ s0, const float* __restrict__ s1,
               const float* __restrict__ s2, bf16* __restrict__ d0,
               bf16* __restrict__ d1, bf16* __restrict__ d2,
               int n0, int n1, int n2)
{
    const int total = n0 + n1 + n2;
    for (int t = blockIdx.x * 256 + threadIdx.x; t < total;
         t += gridDim.x * 256) {
        const float* s; bf16* d; int i;
        if (t < n0)           { s = s0; d = d0; i = t; }
        else if (t < n0 + n1) { s = s1; d = d1; i = t - n0; }
        else                  { s = s2; d = d2; i = t - n0 - n1; }
        float4 v = ((const float4*)s)[i];
        bf16x4 o = { (bf16)v.x, (bf16)v.y, (bf16)v.z, (bf16)v.w };
        ((bf16x4*)d)[i] = o;
    }
}

__global__ __launch_bounds__(256)
void cvt3_k(const float* s0, const float* s1, const float* s2,
            bf16* d0, bf16* d1, bf16* d2)
{ cvt_phase(s0, s1, s2, d0, d1, d2, 786432, 442368, 147456); }

// ---------------------------------------------------------------------------
// GEMM tile body: C[m][n] = sum_k A[m][k]*W[n][k] (+bias). bf16 operands,
// async global_load_lds(16B) staging, TM x 128 tile, BK=32 (R8-R13 proven).
// TM=64 for both GEMMs now: more blocks -> latency-bound grids get 2x
// co-residency (R11 GEMM2 experiment won with this; R10 profile showed
// the family is latency-bound, MfmaUtil 11% / Occupancy 17%).
// ---------------------------------------------------------------------------
template<typename CT, int TM, int K, int LDA, int LDC>
__device__ __forceinline__
void gemm_tile(const bf16* __restrict__ A, const bf16* __restrict__ W,
               CT* __restrict__ C, const float* __restrict__ bias,
               bf16* As, bf16* Bs, int row0, int col0)
{
    constexpr int MI = TM / 32;
    const int tid  = threadIdx.x;
    const int lane = tid & 63;
    const int wave = tid >> 6;
    const int wm = (wave & 1) * (TM / 2);
    const int wn = (wave >> 1) * 64;

    floatx4 acc[MI][4] = {};
    const int fr = lane & 15;
    const int fk = (lane >> 4) * 8;
    const int lr = lane >> 2;        // staging: row within 16-row chunk
    const int lk = (lane & 3) * 8;   //          k offset within row

    for (int k0 = 0; k0 < K; k0 += 32) {
        constexpr int CAW = TM / 64;     // A chunks per wave
        #pragma unroll
        for (int c = 0; c < CAW; ++c) {
            const int chunk = wave * CAW + c;
            const int r = chunk * 16 + lr;
            const bf16* gA = A + (size_t)(row0 + r) * LDA + k0 + lk;
            __builtin_amdgcn_global_load_lds((const GLOBAL_AS void*)gA,
                                             (LDS_AS void*)(As + chunk * 512),
                                             16, 0, 0);
        }
        #pragma unroll
        for (int c = 0; c < 2; ++c) {
            const int chunk = wave * 2 + c;
            const int r = chunk * 16 + lr;
            const bf16* gB = W + (size_t)(col0 + r) * K + k0 + lk;
            __builtin_amdgcn_global_load_lds((const GLOBAL_AS void*)gB,
                                             (LDS_AS void*)(Bs + chunk * 512),
                                             16, 0, 0);
        }
        __syncthreads();

        bf16x8 af[MI], bfr[4];
        #pragma unroll
        for (int i = 0; i < MI; ++i)
            af[i]  = *(const bf16x8*)(As + (wm + i * 16 + fr) * 32 + fk);
        #pragma unroll
        for (int j = 0; j < 4; ++j)
            bfr[j] = *(const bf16x8*)(Bs + (wn + j * 16 + fr) * 32 + fk);
        #pragma unroll
        for (int i = 0; i < MI; ++i)
            #pragma unroll
            for (int j = 0; j < 4; ++j)
                acc[i][j] = __builtin_amdgcn_mfma_f32_16x16x32_bf16(
                    af[i], bfr[j], acc[i][j], 0, 0, 0);

        __syncthreads();
    }

    const int fc  = lane & 15;
    const int fr4 = (lane >> 4) * 4;
    #pragma unroll
    for (int i = 0; i < MI; ++i) {
        #pragma unroll
        for (int j = 0; j < 4; ++j) {
            const int col = col0 + wn + j * 16 + fc;
            const float b = bias ? bias[col] : 0.0f;
            #pragma unroll
            for (int r = 0; r < 4; ++r) {
                const int row = row0 + wm + i * 16 + fr4 + r;
                C[(size_t)row * LDC + col] = (CT)(acc[i][j][r] + b);
            }
        }
    }
}

__global__ __launch_bounds__(256, 2)
void gemm1_k(const bf16* A, const bf16* W, bf16* C)
{
    __shared__ __align__(16) bf16 As[64 * 32];
    __shared__ __align__(16) bf16 Bs[128 * 32];
    gemm_tile<bf16, 64, 768, 768, 2304>(A, W, C, nullptr, As, Bs,
                                        blockIdx.x * 64, blockIdx.y * 128);
}

__global__ __launch_bounds__(256, 2)
void gemm2_k(const bf16* A, const bf16* W, float* C, const float* bias)
{
    __shared__ __align__(16) bf16 As[64 * 32];
    __shared__ __align__(16) bf16 Bs[128 * 32];
    gemm_tile<float, 64, 768, 768, 768>(A, W, C, bias, As, Bs,
                                        blockIdx.x * 64, blockIdx.y * 128);
}

// ---------------------------------------------------------------------------
// Local-window attention, R12/R13-verified variant: K and Q fragments direct
// from global (k-contiguous rows), wave-private LDS only (Vt transpose + P
// layout round-trip), zero __syncthreads. One wave per (b,h,16-i-tile).
// ---------------------------------------------------------------------------
__device__ __forceinline__
void attn_block(const bf16* __restrict__ qkv, bf16* __restrict__ aout,
                char* smem, int blk)
{
    const int w    = threadIdx.x >> 6;
    const int lane = threadIdx.x & 63;
    const int c    = lane & 15;
    const int q    = lane >> 4;
    const int wid  = blk * 4 + w;          // 0..3071
    const int it   = wid & 127;
    const int bh   = wid >> 7;             // 0..23
    const int h    = bh % 12;
    const int b    = bh / 12;
    const int I0   = it * 16;
    const int bbase = b * 2048;
    const int j0   = I0 - 7;

    bf16* Vt = (bf16*)smem           + w * (64 * 40);
    bf16* Ps = (bf16*)(smem + 20480) + w * (16 * 40);

    #pragma unroll
    for (int itr = 0; itr < 4; ++itr) {
        int idx = itr * 64 + lane;        // 0..255
        int row = idx >> 3;               // 0..31
        int dc  = (idx & 7) * 8;          // 0,8,...,56
        int jc  = j0 + row; jc = jc < 0 ? 0 : (jc > 2047 ? 2047 : jc);
        bf16x8 vv = *(const bf16x8*)(qkv + (size_t)(bbase + jc) * 2304
                                     + 1536 + h * 64 + dc);
        #pragma unroll
        for (int e = 0; e < 8; ++e) Vt[(dc + e) * 40 + row] = vv[e];
    }

    const bf16* qrow = qkv + (size_t)(bbase + I0 + c) * 2304 + h * 64;
    bf16x8 aq0 = *(const bf16x8*)(qrow + q * 8);
    bf16x8 aq1 = *(const bf16x8*)(qrow + 32 + q * 8);

    floatx4 st[2] = {};
    #pragma unroll
    for (int t = 0; t < 2; ++t) {
        int jc = j0 + t * 16 + c; jc = jc < 0 ? 0 : (jc > 2047 ? 2047 : jc);
        const bf16* krow = qkv + (size_t)(bbase + jc) * 2304 + 768 + h * 64;
        bf16x8 k0 = *(const bf16x8*)(krow + q * 8);
        bf16x8 k1 = *(const bf16x8*)(krow + 32 + q * 8);
        st[t] = __builtin_amdgcn_mfma_f32_16x16x32_bf16(aq0, k0, st[t], 0, 0, 0);
        st[t] = __builtin_amdgcn_mfma_f32_16x16x32_bf16(aq1, k1, st[t], 0, 0, 0);
    }

    float s[2][4];
    #pragma unroll
    for (int t = 0; t < 2; ++t)
        #pragma unroll
        for (int r = 0; r < 4; ++r) {
            int il = q * 4 + r;
            int jl = t * 16 + c;
            int ja = j0 + jl;
            bool valid = (jl >= il) && (jl <= il + 14) && (ja >= 0) && (ja < 2048);
            s[t][r] = valid ? st[t][r] * 0.125f : -1e30f;
        }

    float l[4], p[2][4];
    #pragma unroll
    for (int r = 0; r < 4; ++r) {
        float m2 = fmaxf(s[0][r], s[1][r]);
        #pragma unroll
        for (int mk = 1; mk < 16; mk <<= 1) m2 = fmaxf(m2, __shfl_xor(m2, mk, 64));
        p[0][r] = __expf(s[0][r] - m2);
        p[1][r] = __expf(s[1][r] - m2);
        float l2 = p[0][r] + p[1][r];
        #pragma unroll
        for (int mk = 1; mk < 16; mk <<= 1) l2 += __shfl_xor(l2, mk, 64);
        l[r] = l2;
    }

    #pragma unroll
    for (int r = 0; r < 4; ++r) {
        Ps[(q * 4 + r) * 40 + c]      = (bf16)p[0][r];
        Ps[(q * 4 + r) * 40 + 16 + c] = (bf16)p[1][r];
    }

    bf16x8 ap = *(const bf16x8*)(&Ps[c * 40 + q * 8]);
    floatx4 ov[4];
    #pragma unroll
    for (int nt = 0; nt < 4; ++nt) {
        bf16x8 vf = *(const bf16x8*)(&Vt[(nt * 16 + c) * 40 + q * 8]);
        floatx4 z = {};
        ov[nt] = __builtin_amdgcn_mfma_f32_16x16x32_bf16(ap, vf, z, 0, 0, 0);
    }

    float rl[4];
    #pragma unroll
    for (int r = 0; r < 4; ++r) rl[r] = 1.0f / l[r];
    #pragma unroll
    for (int r = 0; r < 4; ++r) {
        bf16* orow = aout + (size_t)(bbase + I0 + q * 4 + r) * 768 + h * 64;
        #pragma unroll
        for (int nt = 0; nt < 4; ++nt)
            orow[nt * 16 + c] = (bf16)(ov[nt][r] * rl[r]);
    }
}

__global__ __launch_bounds__(256)
void attn_k(const bf16* qkv, bf16* aout)
{
    __shared__ __align__(16) char smem[25600];
    attn_block(qkv, aout, smem, blockIdx.x);
}

// ---------------------------------------------------------------------------
extern "C" void kernel_launch(void* const* d_in, const int* in_sizes, int n_in,
                              void* d_out, int out_size, void* d_ws, size_t ws_size,
                              hipStream_t stream)
{
    const float* x      = (const float*)d_in[0];  // [4096][768] f32
    const float* w_qkv  = (const float*)d_in[1];  // [2304][768] f32
    const float* w_proj = (const float*)d_in[2];  // [768][768]  f32
    const float* b_proj = (const float*)d_in[3];  // [768]       f32
    float* out = (float*)d_out;                   // [4096][768] f32

    bf16* qkv  = (bf16*)d_ws;                     // [4096][2304]
    bf16* aout = qkv  + (size_t)4096 * 2304;      // [4096][768]
    bf16* xb   = aout + (size_t)4096 * 768;       // [4096][768]
    bf16* wqb  = xb   + (size_t)4096 * 768;       // [2304][768]
    bf16* wpb  = wqb  + (size_t)2304 * 768;       // [768][768]

    // 0) f32 -> bf16 (x, w_qkv, w_proj)
    cvt3_k<<<dim3(1376), 256, 0, stream>>>(x, w_qkv, w_proj, xb, wqb, wpb);

    // 1) qkv = xb @ wqb^T    (TM=64: 1152 blocks, 4.5/CU)
    gemm1_k<<<dim3(64, 18), 256, 0, stream>>>(xb, wqb, qkv);

    // 2) local-window attention -> dense aout
    attn_k<<<dim3(768), 256, 0, stream>>>(qkv, aout);

    // 3) out = aout @ wpb^T + b_proj   (TM=64: 384 blocks)
    gemm2_k<<<dim3(64, 6), 256, 0, stream>>>(aout, wpb, out, b_proj);
}

// Round 15
// 123.922 us; speedup vs baseline: 3.8767x; 1.0088x over previous
//
#include <hip/hip_runtime.h>
#include <hip/hip_bf16.h>

typedef __bf16 bf16;
typedef bf16 bf16x4 __attribute__((ext_vector_type(4)));
typedef bf16 bf16x8 __attribute__((ext_vector_type(8)));
typedef float floatx4 __attribute__((ext_vector_type(4)));

#define GLOBAL_AS __attribute__((address_space(1)))
#define LDS_AS __attribute__((address_space(3)))

// ---------------------------------------------------------------------------
// f32 -> bf16 conversion (grid-stride, float4 granular). R9/R10 A/B-proven.
// ---------------------------------------------------------------------------
__device__ __forceinline__
void cvt_phase(const float* __restrict__ s0, const float* __restrict__ s1,
               const float* __restrict__ s2, bf16* __restrict__ d0,
               bf16* __restrict__ d1, bf16* __restrict__ d2,
               int n0, int n1, int n2)
{
    const int total = n0 + n1 + n2;
    for (int t = blockIdx.x * 256 + threadIdx.x; t < total;
         t += gridDim.x * 256) {
        const float* s; bf16* d; int i;
        if (t < n0)           { s = s0; d = d0; i = t; }
        else if (t < n0 + n1) { s = s1; d = d1; i = t - n0; }
        else                  { s = s2; d = d2; i = t - n0 - n1; }
        float4 v = ((const float4*)s)[i];
        bf16x4 o = { (bf16)v.x, (bf16)v.y, (bf16)v.z, (bf16)v.w };
        ((bf16x4*)d)[i] = o;
    }
}

__global__ __launch_bounds__(256)
void cvt3_k(const float* s0, const float* s1, const float* s2,
            bf16* d0, bf16* d1, bf16* d2)
{ cvt_phase(s0, s1, s2, d0, d1, d2, 786432, 442368, 147456); }

// ---------------------------------------------------------------------------
// GEMM tile body: C[m][n] = sum_k A[m][k]*W[n][k] (+bias). bf16 operands,
// async global_load_lds(16B) staging, TM x 128 tile, BK-step K-loop.
// BK=64 (new): halves barrier-drain count vs BK=32 — the K-loop is
// latency-bound (R10: MfmaUtil 11%, both pipes idle at 2 blocks/CU), so
// exposed DMA latency scales with iteration count. LDS stays <= 32 KB ->
// 2 blocks/CU preserved (m132's BK=128 regression was an occupancy loss).
// Same FP accumulation order as BK=32 -> bit-identical output.
// ---------------------------------------------------------------------------
template<typename CT, int TM, int BK, int K, int LDA, int LDC>
__device__ __forceinline__
void gemm_tile(const bf16* __restrict__ A, const bf16* __restrict__ W,
               CT* __restrict__ C, const float* __restrict__ bias,
               bf16* As, bf16* Bs, int row0, int col0)
{
    constexpr int MI  = TM / 32;          // acc rows per wave
    constexpr int RPC = 512 / BK;         // rows per 1 KB chunk
    constexpr int CA  = TM * BK / 2048;   // A chunks per wave
    constexpr int CB  = 128 * BK / 2048;  // B chunks per wave

    const int tid  = threadIdx.x;
    const int lane = tid & 63;
    const int wave = tid >> 6;
    const int wm = (wave & 1) * (TM / 2);
    const int wn = (wave >> 1) * 64;

    floatx4 acc[MI][4] = {};
    const int fr = lane & 15;
    const int fk = (lane >> 4) * 8;
    const int lr = lane / (BK / 8);          // staging: row within chunk
    const int lk = (lane % (BK / 8)) * 8;    //          k offset within row

    for (int k0 = 0; k0 < K; k0 += BK) {
        #pragma unroll
        for (int c = 0; c < CA; ++c) {
            const int chunk = wave * CA + c;
            const int r = chunk * RPC + lr;
            const bf16* gA = A + (size_t)(row0 + r) * LDA + k0 + lk;
            __builtin_amdgcn_global_load_lds((const GLOBAL_AS void*)gA,
                                             (LDS_AS void*)(As + chunk * 512),
                                             16, 0, 0);
        }
        #pragma unroll
        for (int c = 0; c < CB; ++c) {
            const int chunk = wave * CB + c;
            const int r = chunk * RPC + lr;
            const bf16* gB = W + (size_t)(col0 + r) * K + k0 + lk;
            __builtin_amdgcn_global_load_lds((const GLOBAL_AS void*)gB,
                                             (LDS_AS void*)(Bs + chunk * 512),
                                             16, 0, 0);
        }
        __syncthreads();

        #pragma unroll
        for (int kk = 0; kk < BK / 32; ++kk) {
            bf16x8 af[MI], bfr[4];
            #pragma unroll
            for (int i = 0; i < MI; ++i)
                af[i]  = *(const bf16x8*)(As + (wm + i * 16 + fr) * BK
                                          + kk * 32 + fk);
            #pragma unroll
            for (int j = 0; j < 4; ++j)
                bfr[j] = *(const bf16x8*)(Bs + (wn + j * 16 + fr) * BK
                                          + kk * 32 + fk);
            #pragma unroll
            for (int i = 0; i < MI; ++i)
                #pragma unroll
                for (int j = 0; j < 4; ++j)
                    acc[i][j] = __builtin_amdgcn_mfma_f32_16x16x32_bf16(
                        af[i], bfr[j], acc[i][j], 0, 0, 0);
        }

        __syncthreads();
    }

    const int fc  = lane & 15;
    const int fr4 = (lane >> 4) * 4;
    #pragma unroll
    for (int i = 0; i < MI; ++i) {
        #pragma unroll
        for (int j = 0; j < 4; ++j) {
            const int col = col0 + wn + j * 16 + fc;
            const float b = bias ? bias[col] : 0.0f;
            #pragma unroll
            for (int r = 0; r < 4; ++r) {
                const int row = row0 + wm + i * 16 + fr4 + r;
                C[(size_t)row * LDC + col] = (CT)(acc[i][j][r] + b);
            }
        }
    }
}

__global__ __launch_bounds__(256, 2)
void gemm1_k(const bf16* A, const bf16* W, bf16* C)
{
    __shared__ __align__(16) bf16 As[128 * 64];   // 16 KB
    __shared__ __align__(16) bf16 Bs[128 * 64];   // 16 KB
    gemm_tile<bf16, 128, 64, 768, 768, 2304>(A, W, C, nullptr, As, Bs,
                                             blockIdx.x * 128, blockIdx.y * 128);
}

__global__ __launch_bounds__(256, 2)
void gemm2_k(const bf16* A, const bf16* W, float* C, const float* bias)
{
    __shared__ __align__(16) bf16 As[64 * 64];    // 8 KB
    __shared__ __align__(16) bf16 Bs[128 * 64];   // 16 KB
    gemm_tile<float, 64, 64, 768, 768, 768>(A, W, C, bias, As, Bs,
                                            blockIdx.x * 64, blockIdx.y * 128);
}

// ---------------------------------------------------------------------------
// Local-window attention, R12-R14 verified: K/Q fragments direct from global,
// wave-private LDS (Vt transpose + P layout round-trip), no __syncthreads.
// One wave per (b,h,16-i-tile).
// ---------------------------------------------------------------------------
__device__ __forceinline__
void attn_block(const bf16* __restrict__ qkv, bf16* __restrict__ aout,
                char* smem, int blk)
{
    const int w    = threadIdx.x >> 6;
    const int lane = threadIdx.x & 63;
    const int c    = lane & 15;
    const int q    = lane >> 4;
    const int wid  = blk * 4 + w;          // 0..3071
    const int it   = wid & 127;
    const int bh   = wid >> 7;             // 0..23
    const int h    = bh % 12;
    const int b    = bh / 12;
    const int I0   = it * 16;
    const int bbase = b * 2048;
    const int j0   = I0 - 7;

    bf16* Vt = (bf16*)smem           + w * (64 * 40);
    bf16* Ps = (bf16*)(smem + 20480) + w * (16 * 40);

    #pragma unroll
    for (int itr = 0; itr < 4; ++itr) {
        int idx = itr * 64 + lane;        // 0..255
        int row = idx >> 3;               // 0..31
        int dc  = (idx & 7) * 8;          // 0,8,...,56
        int jc  = j0 + row; jc = jc < 0 ? 0 : (jc > 2047 ? 2047 : jc);
        bf16x8 vv = *(const bf16x8*)(qkv + (size_t)(bbase + jc) * 2304
                                     + 1536 + h * 64 + dc);
        #pragma unroll
        for (int e = 0; e < 8; ++e) Vt[(dc + e) * 40 + row] = vv[e];
    }

    const bf16* qrow = qkv + (size_t)(bbase + I0 + c) * 2304 + h * 64;
    bf16x8 aq0 = *(const bf16x8*)(qrow + q * 8);
    bf16x8 aq1 = *(const bf16x8*)(qrow + 32 + q * 8);

    floatx4 st[2] = {};
    #pragma unroll
    for (int t = 0; t < 2; ++t) {
        int jc = j0 + t * 16 + c; jc = jc < 0 ? 0 : (jc > 2047 ? 2047 : jc);
        const bf16* krow = qkv + (size_t)(bbase + jc) * 2304 + 768 + h * 64;
        bf16x8 k0 = *(const bf16x8*)(krow + q * 8);
        bf16x8 k1 = *(const bf16x8*)(krow + 32 + q * 8);
        st[t] = __builtin_amdgcn_mfma_f32_16x16x32_bf16(aq0, k0, st[t], 0, 0, 0);
        st[t] = __builtin_amdgcn_mfma_f32_16x16x32_bf16(aq1, k1, st[t], 0, 0, 0);
    }

    float s[2][4];
    #pragma unroll
    for (int t = 0; t < 2; ++t)
        #pragma unroll
        for (int r = 0; r < 4; ++r) {
            int il = q * 4 + r;
            int jl = t * 16 + c;
            int ja = j0 + jl;
            bool valid = (jl >= il) && (jl <= il + 14) && (ja >= 0) && (ja < 2048);
            s[t][r] = valid ? st[t][r] * 0.125f : -1e30f;
        }

    float l[4], p[2][4];
    #pragma unroll
    for (int r = 0; r < 4; ++r) {
        float m2 = fmaxf(s[0][r], s[1][r]);
        #pragma unroll
        for (int mk = 1; mk < 16; mk <<= 1) m2 = fmaxf(m2, __shfl_xor(m2, mk, 64));
        p[0][r] = __expf(s[0][r] - m2);
        p[1][r] = __expf(s[1][r] - m2);
        float l2 = p[0][r] + p[1][r];
        #pragma unroll
        for (int mk = 1; mk < 16; mk <<= 1) l2 += __shfl_xor(l2, mk, 64);
        l[r] = l2;
    }

    #pragma unroll
    for (int r = 0; r < 4; ++r) {
        Ps[(q * 4 + r) * 40 + c]      = (bf16)p[0][r];
        Ps[(q * 4 + r) * 40 + 16 + c] = (bf16)p[1][r];
    }

    bf16x8 ap = *(const bf16x8*)(&Ps[c * 40 + q * 8]);
    floatx4 ov[4];
    #pragma unroll
    for (int nt = 0; nt < 4; ++nt) {
        bf16x8 vf = *(const bf16x8*)(&Vt[(nt * 16 + c) * 40 + q * 8]);
        floatx4 z = {};
        ov[nt] = __builtin_amdgcn_mfma_f32_16x16x32_bf16(ap, vf, z, 0, 0, 0);
    }

    float rl[4];
    #pragma unroll
    for (int r = 0; r < 4; ++r) rl[r] = 1.0f / l[r];
    #pragma unroll
    for (int r = 0; r < 4; ++r) {
        bf16* orow = aout + (size_t)(bbase + I0 + q * 4 + r) * 768 + h * 64;
        #pragma unroll
        for (int nt = 0; nt < 4; ++nt)
            orow[nt * 16 + c] = (bf16)(ov[nt][r] * rl[r]);
    }
}

__global__ __launch_bounds__(256)
void attn_k(const bf16* qkv, bf16* aout)
{
    __shared__ __align__(16) char smem[25600];
    attn_block(qkv, aout, smem, blockIdx.x);
}

// ---------------------------------------------------------------------------
extern "C" void kernel_launch(void* const* d_in, const int* in_sizes, int n_in,
                              void* d_out, int out_size, void* d_ws, size_t ws_size,
                              hipStream_t stream)
{
    const float* x      = (const float*)d_in[0];  // [4096][768] f32
    const float* w_qkv  = (const float*)d_in[1];  // [2304][768] f32
    const float* w_proj = (const float*)d_in[2];  // [768][768]  f32
    const float* b_proj = (const float*)d_in[3];  // [768]       f32
    float* out = (float*)d_out;                   // [4096][768] f32

    bf16* qkv  = (bf16*)d_ws;                     // [4096][2304]
    bf16* aout = qkv  + (size_t)4096 * 2304;      // [4096][768]
    bf16* xb   = aout + (size_t)4096 * 768;       // [4096][768]
    bf16* wqb  = xb   + (size_t)4096 * 768;       // [2304][768]
    bf16* wpb  = wqb  + (size_t)2304 * 768;       // [768][768]

    // 0) f32 -> bf16 (x, w_qkv, w_proj)
    cvt3_k<<<dim3(1376), 256, 0, stream>>>(x, w_qkv, w_proj, xb, wqb, wpb);

    // 1) qkv = xb @ wqb^T   (TM=128 restored per R14, BK=64: 12 K-iters)
    gemm1_k<<<dim3(32, 18), 256, 0, stream>>>(xb, wqb, qkv);

    // 2) local-window attention -> dense aout
    attn_k<<<dim3(768), 256, 0, stream>>>(qkv, aout);

    // 3) out = aout @ wpb^T + b_proj   (TM=64, BK=64)
    gemm2_k<<<dim3(64, 6), 256, 0, stream>>>(aout, wpb, out, b_proj);
}